// Round 15
// baseline (581.906 us; speedup 1.0000x reference)
//
#include <hip/hip_runtime.h>

// Linear-chain CRF log-partition (backward DP), B=64, S=1024, T=128.
//
// r15: single wave per chain (no barrier, no waitcnt drain) with the matvec
// done by MFMA so that E can live in AGPRs at ZERO per-use cost.
// r13 proved a 128-word E table gets demoted and v_dot2 can't read AGPRs
// (move per use, +500 cyc/step); r14 proved a single wave cannot cover
// 128x128 E with <128 words/lane (half the rows were simply missing -> NaN).
// MFMA resolves the conflict: A/B operands read AGPRs natively.
//
//   E as 32 A-fragments of v_mfma_f32_16x16x32_f16: row-tile t in [0,8),
//   K-tile k4 in [0,4); lane holds A[m=l&15][k=32*k4+8*(l>>4)+j], j=0..7.
//   v' replicated across all 16 B columns: B[n][k]=v'[k] -> lane's B frag =
//   one broadcast ds_read_b128 per K-tile (4/step). D replicated over cols:
//   lane holds rows 16*t + 4*(l>>4) + [0,4) of every tile t (C/D layout
//   col=lane&15, row=(lane>>4)*4+reg -- HW-verified m89/m91). Lane publishes
//   tile tR=l&7 (2x lane duplication over bit 3 -- same data, same address).
//   A/B k-permutation robustness: both operands use the same (quad,j)->k
//   fill, so any internal k-permutation cancels in the dot product.
//
// Numerics (dead-beat, r13-proven): z = readfirstlane(y[row0]) (exact, lane
// 0 holds row 0); publish v' = y * u * e^{-GHAT} * rcp(z) (f16); y <- E v'
// (f32 MFMA accumulate); Lam += GHAT + log z. Level bounded, f16-safe.
// W via per-64-step ballot mask; 4-deep float4 em prefetch (vmcnt never
// drained -- no barrier/waitcnt anywhere in the hot loop).

typedef __fp16 hv8 __attribute__((ext_vector_type(8)));
typedef __fp16 hp2 __attribute__((ext_vector_type(2)));
typedef float  fv4 __attribute__((ext_vector_type(4)));

#define B_  64
#define S_  1024
#define T_  128
#define PAD_IDX 0
#define EOS_IDX 3
#define BOT_IDX 1
#define GHAT         5.35f
#define EXP_NEG_GHAT 0.004736892f   // e^{-5.35}

static __device__ __forceinline__ unsigned pack2(float a, float b) {
  hp2 h = __builtin_amdgcn_cvt_pkrtz(a, b);
  return __builtin_bit_cast(unsigned, h);
}

__global__ __launch_bounds__(64)
__attribute__((amdgpu_waves_per_eu(1, 1)))
void crf_logz_kernel(
    const int*   __restrict__ W,
    const float* __restrict__ emissions,
    const float* __restrict__ transitions,
    float*       __restrict__ out)
{
  const int b   = blockIdx.x;
  const int l   = threadIdx.x;      // lane 0..63
  const int m16 = l & 15;           // A-row within tile (D col, replicated)
  const int qd  = l >> 4;           // quad 0..3
  const int tR  = l & 7;            // publish tile; rows 16*tR + 4*qd + [0,4)

  __shared__ __align__(16) unsigned vbuf[T_ / 2];   // 128 halves

  // ---- E as MFMA A-fragments: Af[t][k4], m = 16t + m16, k = 32*k4 + 8*qd + j
  hv8 Af[8][4];
  #pragma unroll
  for (int t = 0; t < 8; ++t) {
    #pragma unroll
    for (int k4 = 0; k4 < 4; ++k4) {
      const float* src = transitions + (size_t)(16 * t + m16) * T_ + 32 * k4 + 8 * qd;
      hv8 f;
      #pragma unroll
      for (int j = 0; j < 8; ++j) f[j] = (__fp16)__expf(src[j]);
      Af[t][k4] = f;
    }
  }

  const int roff = 16 * tR + 4 * qd;            // first published row
  const int*    Wrow = W + b * S_;
  const float4* emb4 = (const float4*)(emissions + (size_t)b * S_ * T_ + roff);
  // emb4[i * 32] = em[b, i, roff .. roff+3]

  fv4   y   = {1.f, 1.f, 1.f, 1.f};   // state rows roff..roff+3; Beta = log y + Lam
  float Lam = 0.0f;

  // 4-deep em prefetch: slot0 holds consumed index i
  float4 e0 = emb4[(size_t)(S_ - 1) * 32];
  float4 e1 = emb4[(size_t)(S_ - 2) * 32];
  float4 e2 = emb4[(size_t)(S_ - 3) * 32];
  float4 e3 = emb4[(size_t)(S_ - 4) * 32];
  float4 us0, us1;
  us0.x = __expf(e0.x) * EXP_NEG_GHAT; us0.y = __expf(e0.y) * EXP_NEG_GHAT;
  us0.z = __expf(e0.z) * EXP_NEG_GHAT; us0.w = __expf(e0.w) * EXP_NEG_GHAT;
  us1.x = __expf(e1.x) * EXP_NEG_GHAT; us1.y = __expf(e1.y) * EXP_NEG_GHAT;
  us1.z = __expf(e1.z) * EXP_NEG_GHAT; us1.w = __expf(e1.w) * EXP_NEG_GHAT;

  for (int c = 15; c >= 0; --c) {
    // one vector load of 64 token ids -> uniform 64-bit activity mask (SGPRs)
    int wtok = Wrow[(c << 6) + l];
    unsigned long long m = __ballot((wtok != PAD_IDX) & (wtok != EOS_IDX));
    const int lo = (c == 0) ? 1 : 0;          // i==0 is never consumed

    for (int bit = 63; bit >= lo; --bit) {
      const int i = (c << 6) + bit;           // consumed emission index
      int pf = i - 4; if (pf < 0) pf = 0;     // clamped tail re-read: harmless
      float4 en = emb4[(size_t)pf * 32];      // prefetch (vmcnt, never drained)

      const bool active = (long long)m < 0;   // top bit
      m <<= 1;

      if (active) {                           // wave-uniform branch
        // z = y[row 0]: lane 0 has tR=0, qd=0, reg 0 -> exact, zero staleness
        float z = __builtin_bit_cast(float,
            __builtin_amdgcn_readfirstlane(__builtin_bit_cast(int, y[0])));
        float rz = __builtin_amdgcn_rcpf(z);  // uniform
        // publish v'[roff..roff+3] = y * us * rz  (f16, unnormalized-level)
        unsigned w0 = pack2(y[0] * us0.x * rz, y[1] * us0.y * rz);
        unsigned w1 = pack2(y[2] * us0.z * rz, y[3] * us0.w * rz);
        *(uint2*)&vbuf[(roff >> 1)] = make_uint2(w0, w1);   // ds_write_b64
        asm volatile("" ::: "memory");        // compile-time order only; the
                                              // wave's DS pipe is in-order
        // B fragments: v'[32*k4 + 8*qd + j]  (broadcast ds_read_b128)
        const uint4* vb = (const uint4*)vbuf;
        hv8 B0 = __builtin_bit_cast(hv8, vb[qd]);
        hv8 B1 = __builtin_bit_cast(hv8, vb[4 + qd]);
        hv8 B2 = __builtin_bit_cast(hv8, vb[8 + qd]);
        hv8 B3 = __builtin_bit_cast(hv8, vb[12 + qd]);

        fv4 ynew = {0.f, 0.f, 0.f, 0.f};
        #pragma unroll
        for (int t = 0; t < 8; ++t) {         // 8 independent 4-chains
          fv4 cc = {0.f, 0.f, 0.f, 0.f};
          cc = __builtin_amdgcn_mfma_f32_16x16x32_f16(Af[t][0], B0, cc, 0, 0, 0);
          cc = __builtin_amdgcn_mfma_f32_16x16x32_f16(Af[t][1], B1, cc, 0, 0, 0);
          cc = __builtin_amdgcn_mfma_f32_16x16x32_f16(Af[t][2], B2, cc, 0, 0, 0);
          cc = __builtin_amdgcn_mfma_f32_16x16x32_f16(Af[t][3], B3, cc, 0, 0, 0);
          if (t == tR) ynew = cc;             // cndmask select (t unrolled)
        }
        y = ynew;
        Lam += GHAT + __logf(z);              // exact compensation (off-path)
      }
      // shift prefetch pipeline
      e0 = e1; us0 = us1;
      e1 = e2;
      e2 = e3;
      e3 = en;
      us1.x = __expf(e1.x) * EXP_NEG_GHAT;
      us1.y = __expf(e1.y) * EXP_NEG_GHAT;
      us1.z = __expf(e1.z) * EXP_NEG_GHAT;
      us1.w = __expf(e1.w) * EXP_NEG_GHAT;
    }
  }

  // ---- epilogue: f_r = trans[BOT,r] + em[b,0,r] + log y_r + Lam
  //      lanes l and l^8 duplicate rows -> mask l&8 out of the reduction
  float4 tb4 = *(const float4*)(transitions + BOT_IDX * T_ + roff);
  float f0 = tb4.x + e0.x + __logf(y[0]);     // e0 ended as em[b,0,roff..]
  float f1 = tb4.y + e0.y + __logf(y[1]);
  float f2 = tb4.z + e0.z + __logf(y[2]);
  float f3 = tb4.w + e0.w + __logf(y[3]);
  float mm = fmaxf(fmaxf(f0, f1), fmaxf(f2, f3));
  if (l & 8) mm = -3.4e38f;
  #pragma unroll
  for (int off = 32; off; off >>= 1) mm = fmaxf(mm, __shfl_xor(mm, off));
  float s = (l & 8) ? 0.0f
          : (__expf(f0 - mm) + __expf(f1 - mm) + __expf(f2 - mm) + __expf(f3 - mm));
  #pragma unroll
  for (int off = 32; off; off >>= 1) s += __shfl_xor(s, off);
  if (l == 0) out[b] = Lam + mm + __logf(s);
}

extern "C" void kernel_launch(void* const* d_in, const int* in_sizes, int n_in,
                              void* d_out, int out_size, void* d_ws, size_t ws_size,
                              hipStream_t stream) {
  const int*   W     = (const int*)d_in[0];
  const float* em    = (const float*)d_in[1];
  const float* trans = (const float*)d_in[2];
  float*       out   = (float*)d_out;
  (void)in_sizes; (void)n_in; (void)out_size; (void)d_ws; (void)ws_size;
  crf_logz_kernel<<<B_, 64, 0, stream>>>(W, em, trans, out);
}